// Round 2
// baseline (2715.370 us; speedup 1.0000x reference)
//
#include <hip/hip_runtime.h>

// RWKV-7 Tmix (B=4, T=1024, C=1024, H=16, HS=64, H_KV=4)
// Round 1: all I/O is float32 (in_npz size matches f32). f32 intermediates in ws.

#define NROWS 4096      // B*T
#define CCH   1024
#define EPSV  0.00064f

// ---------------------------------------------------------------------------
// Tiled f32 GEMM, C[M,N] = A[M,K] * B[N,K]^T.
// BM=BN=64, BK=16, 256 threads, 4x4 per thread.
// ---------------------------------------------------------------------------
__global__ __launch_bounds__(256) void gemm_nt(
    const float* __restrict__ Ap, const float* __restrict__ Bp,
    float* __restrict__ Cp, int M, int N, int K)
{
    __shared__ __align__(16) float As[16][68];
    __shared__ __align__(16) float Bs[16][68];
    const int t  = threadIdx.x;
    const int tx = t & 15, ty = t >> 4;
    const int m0 = blockIdx.y * 64, n0 = blockIdx.x * 64;
    const int lr = t >> 2, lq = t & 3;

    float acc[4][4] = {};

    for (int k0 = 0; k0 < K; k0 += 16) {
        const float4 av = *reinterpret_cast<const float4*>(
            Ap + (size_t)(m0 + lr) * K + k0 + lq * 4);
        const float4 bv = *reinterpret_cast<const float4*>(
            Bp + (size_t)(n0 + lr) * K + k0 + lq * 4);

        As[lq * 4 + 0][lr] = av.x; As[lq * 4 + 1][lr] = av.y;
        As[lq * 4 + 2][lr] = av.z; As[lq * 4 + 3][lr] = av.w;
        Bs[lq * 4 + 0][lr] = bv.x; Bs[lq * 4 + 1][lr] = bv.y;
        Bs[lq * 4 + 2][lr] = bv.z; Bs[lq * 4 + 3][lr] = bv.w;
        __syncthreads();

        #pragma unroll
        for (int kk = 0; kk < 16; ++kk) {
            const float4 a = *reinterpret_cast<const float4*>(&As[kk][ty * 4]);
            const float4 b = *reinterpret_cast<const float4*>(&Bs[kk][tx * 4]);
            acc[0][0] += a.x * b.x; acc[0][1] += a.x * b.y; acc[0][2] += a.x * b.z; acc[0][3] += a.x * b.w;
            acc[1][0] += a.y * b.x; acc[1][1] += a.y * b.y; acc[1][2] += a.y * b.z; acc[1][3] += a.y * b.w;
            acc[2][0] += a.z * b.x; acc[2][1] += a.z * b.y; acc[2][2] += a.z * b.z; acc[2][3] += a.z * b.w;
            acc[3][0] += a.w * b.x; acc[3][1] += a.w * b.y; acc[3][2] += a.w * b.z; acc[3][3] += a.w * b.w;
        }
        __syncthreads();
    }

    #pragma unroll
    for (int i = 0; i < 4; ++i) {
        const size_t row = (size_t)(m0 + ty * 4 + i) * N + n0 + tx * 4;
        *reinterpret_cast<float4*>(Cp + row) =
            make_float4(acc[i][0], acc[i][1], acc[i][2], acc[i][3]);
    }
}

// ---------------------------------------------------------------------------
// Hidden projections: hw = tanh(x@w1) (64), ha = x@a1 (64), hv = x@v1 (32)
// One block per row n, x row staged in LDS.
// ---------------------------------------------------------------------------
__global__ __launch_bounds__(256) void hidden_proj(
    const float* __restrict__ x, const float* __restrict__ w1,
    const float* __restrict__ a1, const float* __restrict__ v1,
    float* __restrict__ hw, float* __restrict__ ha, float* __restrict__ hv)
{
    const int n = blockIdx.x, t = threadIdx.x;
    __shared__ __align__(16) float xs[1024];
    *reinterpret_cast<float4*>(&xs[t * 4]) =
        *reinterpret_cast<const float4*>(x + (size_t)n * 1024 + t * 4);
    __syncthreads();
    const int w = t >> 6, f = t & 63;
    float acc = 0.f;
    if (w == 0) {
        #pragma unroll 8
        for (int c = 0; c < 1024; ++c) acc += xs[c] * w1[c * 64 + f];
        hw[n * 64 + f] = tanhf(acc);
    } else if (w == 1) {
        #pragma unroll 8
        for (int c = 0; c < 1024; ++c) acc += xs[c] * a1[c * 64 + f];
        ha[n * 64 + f] = acc;
    } else if (w == 2 && f < 32) {
        #pragma unroll 8
        for (int c = 0; c < 1024; ++c) acc += xs[c] * v1[c * 32 + f];
        hv[n * 32 + f] = acc;
    }
}

// ---------------------------------------------------------------------------
// Fused pre-recurrence elementwise: decay, a, v-mix, kk-norm, k, aa=-kk, bb=kk*a
// One block per row; each wave = one head (64 channels).
// ---------------------------------------------------------------------------
__global__ __launch_bounds__(256) void fuse_pre(
    const float* __restrict__ kp, const float* __restrict__ vp,
    const float* __restrict__ hw, const float* __restrict__ ha, const float* __restrict__ hv,
    const float* __restrict__ v_first,
    const float* __restrict__ w0, const float* __restrict__ w2,
    const float* __restrict__ a0, const float* __restrict__ a2,
    const float* __restrict__ v0, const float* __restrict__ v2,
    const float* __restrict__ k_k, const float* __restrict__ k_a,
    float* __restrict__ wdec, float* __restrict__ kf, float* __restrict__ vf,
    float* __restrict__ aab, float* __restrict__ bbb)
{
    const int n = blockIdx.x, t = threadIdx.x;
    __shared__ float shw[64], sha[64], shv[32];
    if (t < 64) shw[t] = hw[n * 64 + t];
    else if (t < 128) sha[t - 64] = ha[n * 64 + t - 64];
    else if (t < 160) shv[t - 128] = hv[n * 32 + t - 128];
    __syncthreads();

    #pragma unroll
    for (int q = 0; q < 4; ++q) {
        const int c = q * 256 + t;
        // decay: w = -softplus(-dd) - 0.6 ; dec = exp(-exp(w))
        float dd = w0[c];
        #pragma unroll 8
        for (int d = 0; d < 64; ++d) dd += shw[d] * w2[d * 1024 + c];
        const float u  = -dd;
        const float sp = fmaxf(u, 0.f) + log1pf(expf(-fabsf(u)));   // softplus(-dd)
        const float dec = expf(-expf(-sp - 0.6f));
        // a (in-context lr)
        float aacc = a0[c];
        #pragma unroll 8
        for (int d = 0; d < 64; ++d) aacc += sha[d] * a2[d * 1024 + c];
        const float av = 1.f / (1.f + expf(-aacc));
        // v residual-mix gate
        float vacc = v0[c];
        #pragma unroll 8
        for (int d = 0; d < 32; ++d) vacc += shv[d] * v2[d * 1024 + c];
        const float sv = 1.f / (1.f + expf(-vacc));

        // GQA repeat: channel c -> kv channel (c>>8)*64 + (c&63)
        const int  ck  = q * 64 + (c & 63);
        const float kr = kp[(size_t)n * 256 + ck];
        const float vr = vp[(size_t)n * 256 + ck];
        const float vfi = v_first[(size_t)n * 1024 + c];
        const float vv  = vr + (vfi - vr) * sv;

        // kk = normalize_per_head(k * k_k); wave == one head
        const float tkk = kr * k_k[c];
        float ss = tkk * tkk;
        #pragma unroll
        for (int off = 32; off > 0; off >>= 1) ss += __shfl_xor(ss, off, 64);
        const float kkv = tkk / fmaxf(sqrtf(ss), 1e-12f);

        const size_t idx = (size_t)n * 1024 + c;
        wdec[idx] = dec;
        kf[idx]   = kr * (1.f + (av - 1.f) * k_a[c]);
        vf[idx]   = vv;
        aab[idx]  = -kkv;
        bbb[idx]  = kkv * av;
    }
}

// ---------------------------------------------------------------------------
// WKV7 recurrence: 64 blocks (b,h), 64 threads; thread i owns S[i][0..63].
// ---------------------------------------------------------------------------
__global__ __launch_bounds__(64) void wkv7(
    const float* __restrict__ r, const float* __restrict__ wdec,
    const float* __restrict__ kf, const float* __restrict__ vf,
    const float* __restrict__ aab, const float* __restrict__ bbb,
    const float* __restrict__ mask, float* __restrict__ y)
{
    const int bh = blockIdx.x;
    const int b = bh >> 4, h = bh & 15;
    const int i = threadIdx.x;
    __shared__ __align__(16) float rs[64], ds[64], ks[64], as_[64], bs[64];

    float S[64];
    #pragma unroll
    for (int j = 0; j < 64; ++j) S[j] = 0.f;

    for (int t = 0; t < 1024; ++t) {
        const size_t base = ((size_t)(b * 1024 + t)) * 1024 + h * 64;
        const float m = mask[b * 1024 + t];
        const bool live = m > 0.f;
        rs[i]  = r[base + i];
        ds[i]  = live ? wdec[base + i] : 1.f;
        ks[i]  = kf[base + i] * m;
        as_[i] = aab[base + i] * m;
        bs[i]  = bbb[base + i] * m;
        const float vi = vf[base + i] * m;
        __syncthreads();

        float sa = 0.f;
        #pragma unroll
        for (int jq = 0; jq < 16; ++jq) {
            const float4 a4 = *reinterpret_cast<const float4*>(&as_[jq * 4]);
            sa += S[jq * 4 + 0] * a4.x + S[jq * 4 + 1] * a4.y
                + S[jq * 4 + 2] * a4.z + S[jq * 4 + 3] * a4.w;
        }

        float yacc = 0.f;
        #pragma unroll
        for (int jq = 0; jq < 16; ++jq) {
            const float4 d4 = *reinterpret_cast<const float4*>(&ds[jq * 4]);
            const float4 b4 = *reinterpret_cast<const float4*>(&bs[jq * 4]);
            const float4 k4 = *reinterpret_cast<const float4*>(&ks[jq * 4]);
            const float4 r4 = *reinterpret_cast<const float4*>(&rs[jq * 4]);
            float s;
            s = S[jq * 4 + 0] * d4.x + sa * b4.x + vi * k4.x; S[jq * 4 + 0] = s; yacc += s * r4.x;
            s = S[jq * 4 + 1] * d4.y + sa * b4.y + vi * k4.y; S[jq * 4 + 1] = s; yacc += s * r4.y;
            s = S[jq * 4 + 2] * d4.z + sa * b4.z + vi * k4.z; S[jq * 4 + 2] = s; yacc += s * r4.z;
            s = S[jq * 4 + 3] * d4.w + sa * b4.w + vi * k4.w; S[jq * 4 + 3] = s; yacc += s * r4.w;
        }
        y[base + i] = yacc;
        __syncthreads();
    }
}

// ---------------------------------------------------------------------------
// Post: groupnorm per (row, head) + rk*v residual
// ---------------------------------------------------------------------------
__global__ __launch_bounds__(256) void fuse_post(
    const float* __restrict__ y, const float* __restrict__ r,
    const float* __restrict__ kf, const float* __restrict__ vf,
    const float* __restrict__ r_k, const float* __restrict__ ln_g, const float* __restrict__ ln_b,
    float* __restrict__ yn)
{
    const int n = blockIdx.x, t = threadIdx.x;
    #pragma unroll
    for (int q = 0; q < 4; ++q) {
        const int c = q * 256 + t;
        const size_t idx = (size_t)n * 1024 + c;
        const float yv = y[idx];
        float s1 = yv, s2 = yv * yv;
        float rk = r[idx] * kf[idx] * r_k[c];
        #pragma unroll
        for (int off = 32; off > 0; off >>= 1) {
            s1 += __shfl_xor(s1, off, 64);
            s2 += __shfl_xor(s2, off, 64);
            rk += __shfl_xor(rk, off, 64);
        }
        const float mu  = s1 * (1.f / 64.f);
        const float var = s2 * (1.f / 64.f) - mu * mu;
        yn[idx] = (yv - mu) * rsqrtf(var + EPSV) * ln_g[c] + ln_b[c]
                  + rk * vf[idx];
    }
}

// ---------------------------------------------------------------------------
extern "C" void kernel_launch(void* const* d_in, const int* in_sizes, int n_in,
                              void* d_out, int out_size, void* d_ws, size_t ws_size,
                              hipStream_t stream)
{
    const float* x       = (const float*)d_in[0];
    const float* v_first = (const float*)d_in[1];
    const float* mask    = (const float*)d_in[2];
    const float* Wr      = (const float*)d_in[3];
    const float* Wk      = (const float*)d_in[4];
    const float* Wv      = (const float*)d_in[5];
    const float* Wo      = (const float*)d_in[6];
    const float* w0      = (const float*)d_in[7];
    const float* w1      = (const float*)d_in[8];
    const float* w2      = (const float*)d_in[9];
    const float* a0      = (const float*)d_in[10];
    const float* a1      = (const float*)d_in[11];
    const float* a2      = (const float*)d_in[12];
    const float* v0      = (const float*)d_in[13];
    const float* v1      = (const float*)d_in[14];
    const float* v2      = (const float*)d_in[15];
    const float* k_k     = (const float*)d_in[16];
    const float* k_a     = (const float*)d_in[17];
    const float* r_k     = (const float*)d_in[18];
    const float* ln_g    = (const float*)d_in[19];
    const float* ln_b    = (const float*)d_in[20];
    float* out = (float*)d_out;

    float* ws = (float*)d_ws;
    const size_t M4 = (size_t)NROWS * CCH;   // 4M elements
    float* rbuf = ws;
    float* wdec = ws + 1 * M4;
    float* kf   = ws + 2 * M4;
    float* vf   = ws + 3 * M4;
    float* aab  = ws + 4 * M4;
    float* bbb  = ws + 5 * M4;
    float* ybuf = ws + 6 * M4;
    // aliases inside ybuf region (dead before ybuf is written):
    float* kp = ws + 6 * M4;
    float* vp = kp + (size_t)NROWS * 256;
    float* hw = vp + (size_t)NROWS * 256;
    float* ha = hw + (size_t)NROWS * 64;
    float* hv = ha + (size_t)NROWS * 64;
    // alias aab (dead after wkv7):
    float* yn = aab;

    dim3 blk(256);
    gemm_nt<<<dim3(16, 64), blk, 0, stream>>>(x, Wr, rbuf, NROWS, 1024, 1024);
    gemm_nt<<<dim3(4, 64),  blk, 0, stream>>>(x, Wk, kp,   NROWS,  256, 1024);
    gemm_nt<<<dim3(4, 64),  blk, 0, stream>>>(x, Wv, vp,   NROWS,  256, 1024);
    hidden_proj<<<NROWS, blk, 0, stream>>>(x, w1, a1, v1, hw, ha, hv);
    fuse_pre<<<NROWS, blk, 0, stream>>>(kp, vp, hw, ha, hv, v_first,
                                        w0, w2, a0, a2, v0, v2, k_k, k_a,
                                        wdec, kf, vf, aab, bbb);
    wkv7<<<64, dim3(64), 0, stream>>>(rbuf, wdec, kf, vf, aab, bbb, mask, ybuf);
    fuse_post<<<NROWS, blk, 0, stream>>>(ybuf, rbuf, kf, vf, r_k, ln_g, ln_b, yn);
    gemm_nt<<<dim3(16, 64), blk, 0, stream>>>(yn, Wo, out, NROWS, 1024, 1024);
    hipMemcpyAsync(out + M4, v_first, M4 * sizeof(float),
                   hipMemcpyDeviceToDevice, stream);
}

// Round 3
// 1462.565 us; speedup vs baseline: 1.8566x; 1.8566x over previous
//
#include <hip/hip_runtime.h>

// RWKV-7 Tmix (B=4, T=1024, C=1024, H=16, HS=64, H_KV=4)
// Round 2: wkv7 rewritten — 256 thr/block (4 threads per state row),
// double-buffered LDS (1 barrier/step), depth-2 register prefetch.
// Mask folded into fuse_pre.

#define NROWS 4096      // B*T
#define CCH   1024
#define EPSV  0.00064f

// ---------------------------------------------------------------------------
// Tiled f32 GEMM, C[M,N] = A[M,K] * B[N,K]^T.
// BM=BN=64, BK=16, 256 threads, 4x4 per thread.
// ---------------------------------------------------------------------------
__global__ __launch_bounds__(256) void gemm_nt(
    const float* __restrict__ Ap, const float* __restrict__ Bp,
    float* __restrict__ Cp, int M, int N, int K)
{
    __shared__ __align__(16) float As[16][68];
    __shared__ __align__(16) float Bs[16][68];
    const int t  = threadIdx.x;
    const int tx = t & 15, ty = t >> 4;
    const int m0 = blockIdx.y * 64, n0 = blockIdx.x * 64;
    const int lr = t >> 2, lq = t & 3;

    float acc[4][4] = {};

    for (int k0 = 0; k0 < K; k0 += 16) {
        const float4 av = *reinterpret_cast<const float4*>(
            Ap + (size_t)(m0 + lr) * K + k0 + lq * 4);
        const float4 bv = *reinterpret_cast<const float4*>(
            Bp + (size_t)(n0 + lr) * K + k0 + lq * 4);

        As[lq * 4 + 0][lr] = av.x; As[lq * 4 + 1][lr] = av.y;
        As[lq * 4 + 2][lr] = av.z; As[lq * 4 + 3][lr] = av.w;
        Bs[lq * 4 + 0][lr] = bv.x; Bs[lq * 4 + 1][lr] = bv.y;
        Bs[lq * 4 + 2][lr] = bv.z; Bs[lq * 4 + 3][lr] = bv.w;
        __syncthreads();

        #pragma unroll
        for (int kk = 0; kk < 16; ++kk) {
            const float4 a = *reinterpret_cast<const float4*>(&As[kk][ty * 4]);
            const float4 b = *reinterpret_cast<const float4*>(&Bs[kk][tx * 4]);
            acc[0][0] += a.x * b.x; acc[0][1] += a.x * b.y; acc[0][2] += a.x * b.z; acc[0][3] += a.x * b.w;
            acc[1][0] += a.y * b.x; acc[1][1] += a.y * b.y; acc[1][2] += a.y * b.z; acc[1][3] += a.y * b.w;
            acc[2][0] += a.z * b.x; acc[2][1] += a.z * b.y; acc[2][2] += a.z * b.z; acc[2][3] += a.z * b.w;
            acc[3][0] += a.w * b.x; acc[3][1] += a.w * b.y; acc[3][2] += a.w * b.z; acc[3][3] += a.w * b.w;
        }
        __syncthreads();
    }

    #pragma unroll
    for (int i = 0; i < 4; ++i) {
        const size_t row = (size_t)(m0 + ty * 4 + i) * N + n0 + tx * 4;
        *reinterpret_cast<float4*>(Cp + row) =
            make_float4(acc[i][0], acc[i][1], acc[i][2], acc[i][3]);
    }
}

// ---------------------------------------------------------------------------
// Hidden projections: hw = tanh(x@w1) (64), ha = x@a1 (64), hv = x@v1 (32)
// ---------------------------------------------------------------------------
__global__ __launch_bounds__(256) void hidden_proj(
    const float* __restrict__ x, const float* __restrict__ w1,
    const float* __restrict__ a1, const float* __restrict__ v1,
    float* __restrict__ hw, float* __restrict__ ha, float* __restrict__ hv)
{
    const int n = blockIdx.x, t = threadIdx.x;
    __shared__ __align__(16) float xs[1024];
    *reinterpret_cast<float4*>(&xs[t * 4]) =
        *reinterpret_cast<const float4*>(x + (size_t)n * 1024 + t * 4);
    __syncthreads();
    const int w = t >> 6, f = t & 63;
    float acc = 0.f;
    if (w == 0) {
        #pragma unroll 8
        for (int c = 0; c < 1024; ++c) acc += xs[c] * w1[c * 64 + f];
        hw[n * 64 + f] = tanhf(acc);
    } else if (w == 1) {
        #pragma unroll 8
        for (int c = 0; c < 1024; ++c) acc += xs[c] * a1[c * 64 + f];
        ha[n * 64 + f] = acc;
    } else if (w == 2 && f < 32) {
        #pragma unroll 8
        for (int c = 0; c < 1024; ++c) acc += xs[c] * v1[c * 32 + f];
        hv[n * 32 + f] = acc;
    }
}

// ---------------------------------------------------------------------------
// Fused pre-recurrence elementwise. Mask is applied HERE (wkv7 reads clean
// streams): k,v,aa,bb *= m ; d = (m>0 ? d : 1).
// ---------------------------------------------------------------------------
__global__ __launch_bounds__(256) void fuse_pre(
    const float* __restrict__ kp, const float* __restrict__ vp,
    const float* __restrict__ hw, const float* __restrict__ ha, const float* __restrict__ hv,
    const float* __restrict__ v_first, const float* __restrict__ mask,
    const float* __restrict__ w0, const float* __restrict__ w2,
    const float* __restrict__ a0, const float* __restrict__ a2,
    const float* __restrict__ v0, const float* __restrict__ v2,
    const float* __restrict__ k_k, const float* __restrict__ k_a,
    float* __restrict__ wdec, float* __restrict__ kf, float* __restrict__ vf,
    float* __restrict__ aab, float* __restrict__ bbb)
{
    const int n = blockIdx.x, t = threadIdx.x;
    __shared__ float shw[64], sha[64], shv[32];
    if (t < 64) shw[t] = hw[n * 64 + t];
    else if (t < 128) sha[t - 64] = ha[n * 64 + t - 64];
    else if (t < 160) shv[t - 128] = hv[n * 32 + t - 128];
    __syncthreads();

    const float m = mask[n];
    const bool live = m > 0.f;

    #pragma unroll
    for (int q = 0; q < 4; ++q) {
        const int c = q * 256 + t;
        // decay: w = -softplus(-dd) - 0.6 ; dec = exp(-exp(w))
        float dd = w0[c];
        #pragma unroll 8
        for (int d = 0; d < 64; ++d) dd += shw[d] * w2[d * 1024 + c];
        const float u  = -dd;
        const float sp = fmaxf(u, 0.f) + log1pf(expf(-fabsf(u)));   // softplus(-dd)
        const float dec = expf(-expf(-sp - 0.6f));
        // a (in-context lr)
        float aacc = a0[c];
        #pragma unroll 8
        for (int d = 0; d < 64; ++d) aacc += sha[d] * a2[d * 1024 + c];
        const float av = 1.f / (1.f + expf(-aacc));
        // v residual-mix gate
        float vacc = v0[c];
        #pragma unroll 8
        for (int d = 0; d < 32; ++d) vacc += shv[d] * v2[d * 1024 + c];
        const float sv = 1.f / (1.f + expf(-vacc));

        // GQA repeat: channel c -> kv channel (c>>8)*64 + (c&63)
        const int  ck  = q * 64 + (c & 63);
        const float kr = kp[(size_t)n * 256 + ck];
        const float vr = vp[(size_t)n * 256 + ck];
        const float vfi = v_first[(size_t)n * 1024 + c];
        const float vv  = vr + (vfi - vr) * sv;

        // kk = normalize_per_head(k * k_k); wave == one head
        const float tkk = kr * k_k[c];
        float ss = tkk * tkk;
        #pragma unroll
        for (int off = 32; off > 0; off >>= 1) ss += __shfl_xor(ss, off, 64);
        const float kkv = tkk / fmaxf(sqrtf(ss), 1e-12f);

        const size_t idx = (size_t)n * 1024 + c;
        wdec[idx] = live ? dec : 1.f;
        kf[idx]   = kr * (1.f + (av - 1.f) * k_a[c]) * m;
        vf[idx]   = vv * m;
        aab[idx]  = -kkv * m;
        bbb[idx]  = kkv * av * m;
    }
}

// ---------------------------------------------------------------------------
// WKV7 recurrence. 64 blocks = (b,h); 256 threads; thread (row=tid>>2,
// q=tid&3) owns S[row][16q..16q+15]. Double-buffered LDS, one barrier per
// step, depth-2 global->register prefetch.
// LDS vec ids: 0=r 1=d 2=k 3=aa 4=bb 5=v
// ---------------------------------------------------------------------------
__global__ __launch_bounds__(256) void wkv7(
    const float* __restrict__ r, const float* __restrict__ wdec,
    const float* __restrict__ kf, const float* __restrict__ vf,
    const float* __restrict__ aab, const float* __restrict__ bbb,
    float* __restrict__ y)
{
    const int bh = blockIdx.x;          // 64
    const int b = bh >> 4, h = bh & 15;
    const int tid = threadIdx.x;
    const int row = tid >> 2;
    const int q   = tid & 3;
    const int j0  = q << 4;
    const int lane = tid & 63;
    const int grp  = tid >> 6;          // wave-uniform

    __shared__ __align__(16) float sbuf[2][6][64];

    const size_t bhbase = (size_t)b * 1024 * 1024 + (size_t)h * 64;

    float S[16];
    #pragma unroll
    for (int c = 0; c < 16; ++c) S[c] = 0.f;

    float pA0 = 0.f, pA1 = 0.f, pB0 = 0.f, pB1 = 0.f;

    auto issue = [&](int tt, float& p0, float& p1) {
        const size_t base = bhbase + (size_t)tt * 1024 + lane;
        if (grp == 0)      { p0 = r[base];    p1 = bbb[base]; }
        else if (grp == 1) { p0 = wdec[base]; p1 = vf[base];  }
        else if (grp == 2) { p0 = kf[base];   }
        else               { p0 = aab[base];  }
    };
    auto stash = [&](int buf, float p0, float p1) {
        if (grp == 0)      { sbuf[buf][0][lane] = p0; sbuf[buf][4][lane] = p1; }
        else if (grp == 1) { sbuf[buf][1][lane] = p0; sbuf[buf][5][lane] = p1; }
        else if (grp == 2) { sbuf[buf][2][lane] = p0; }
        else               { sbuf[buf][3][lane] = p0; }
    };
    auto step = [&](int buf, int tt) {
        const float4* ap = reinterpret_cast<const float4*>(&sbuf[buf][3][j0]);
        float sa = 0.f;
        #pragma unroll
        for (int u = 0; u < 4; ++u) {
            const float4 a4 = ap[u];
            sa += S[u*4+0]*a4.x + S[u*4+1]*a4.y + S[u*4+2]*a4.z + S[u*4+3]*a4.w;
        }
        sa += __shfl_xor(sa, 1, 64);
        sa += __shfl_xor(sa, 2, 64);
        const float vi = sbuf[buf][5][row];
        const float4* dp = reinterpret_cast<const float4*>(&sbuf[buf][1][j0]);
        const float4* bp = reinterpret_cast<const float4*>(&sbuf[buf][4][j0]);
        const float4* kp = reinterpret_cast<const float4*>(&sbuf[buf][2][j0]);
        const float4* rp = reinterpret_cast<const float4*>(&sbuf[buf][0][j0]);
        float yp = 0.f;
        #pragma unroll
        for (int u = 0; u < 4; ++u) {
            const float4 d4 = dp[u], b4 = bp[u], k4 = kp[u], r4 = rp[u];
            float s;
            s = S[u*4+0]*d4.x + sa*b4.x + vi*k4.x; S[u*4+0] = s; yp += s*r4.x;
            s = S[u*4+1]*d4.y + sa*b4.y + vi*k4.y; S[u*4+1] = s; yp += s*r4.y;
            s = S[u*4+2]*d4.z + sa*b4.z + vi*k4.z; S[u*4+2] = s; yp += s*r4.z;
            s = S[u*4+3]*d4.w + sa*b4.w + vi*k4.w; S[u*4+3] = s; yp += s*r4.w;
        }
        yp += __shfl_xor(yp, 1, 64);
        yp += __shfl_xor(yp, 2, 64);
        if (q == 0) y[bhbase + (size_t)tt * 1024 + row] = yp;
    };

    issue(0, pA0, pA1);
    issue(1, pB0, pB1);
    stash(0, pA0, pA1);
    __syncthreads();

    for (int t = 0; t < 1024; t += 2) {
        issue(t + 2 < 1024 ? t + 2 : 1023, pA0, pA1);
        step(0, t);
        stash(1, pB0, pB1);
        __syncthreads();
        issue(t + 3 < 1024 ? t + 3 : 1023, pB0, pB1);
        step(1, t + 1);
        stash(0, pA0, pA1);
        __syncthreads();
    }
}

// ---------------------------------------------------------------------------
// Post: groupnorm per (row, head) + rk*v residual
// ---------------------------------------------------------------------------
__global__ __launch_bounds__(256) void fuse_post(
    const float* __restrict__ y, const float* __restrict__ r,
    const float* __restrict__ kf, const float* __restrict__ vf,
    const float* __restrict__ r_k, const float* __restrict__ ln_g, const float* __restrict__ ln_b,
    float* __restrict__ yn)
{
    const int n = blockIdx.x, t = threadIdx.x;
    #pragma unroll
    for (int q = 0; q < 4; ++q) {
        const int c = q * 256 + t;
        const size_t idx = (size_t)n * 1024 + c;
        const float yv = y[idx];
        float s1 = yv, s2 = yv * yv;
        float rk = r[idx] * kf[idx] * r_k[c];
        #pragma unroll
        for (int off = 32; off > 0; off >>= 1) {
            s1 += __shfl_xor(s1, off, 64);
            s2 += __shfl_xor(s2, off, 64);
            rk += __shfl_xor(rk, off, 64);
        }
        const float mu  = s1 * (1.f / 64.f);
        const float var = s2 * (1.f / 64.f) - mu * mu;
        yn[idx] = (yv - mu) * rsqrtf(var + EPSV) * ln_g[c] + ln_b[c]
                  + rk * vf[idx];
    }
}

// ---------------------------------------------------------------------------
extern "C" void kernel_launch(void* const* d_in, const int* in_sizes, int n_in,
                              void* d_out, int out_size, void* d_ws, size_t ws_size,
                              hipStream_t stream)
{
    const float* x       = (const float*)d_in[0];
    const float* v_first = (const float*)d_in[1];
    const float* mask    = (const float*)d_in[2];
    const float* Wr      = (const float*)d_in[3];
    const float* Wk      = (const float*)d_in[4];
    const float* Wv      = (const float*)d_in[5];
    const float* Wo      = (const float*)d_in[6];
    const float* w0      = (const float*)d_in[7];
    const float* w1      = (const float*)d_in[8];
    const float* w2      = (const float*)d_in[9];
    const float* a0      = (const float*)d_in[10];
    const float* a1      = (const float*)d_in[11];
    const float* a2      = (const float*)d_in[12];
    const float* v0      = (const float*)d_in[13];
    const float* v1      = (const float*)d_in[14];
    const float* v2      = (const float*)d_in[15];
    const float* k_k     = (const float*)d_in[16];
    const float* k_a     = (const float*)d_in[17];
    const float* r_k     = (const float*)d_in[18];
    const float* ln_g    = (const float*)d_in[19];
    const float* ln_b    = (const float*)d_in[20];
    float* out = (float*)d_out;

    float* ws = (float*)d_ws;
    const size_t M4 = (size_t)NROWS * CCH;   // 4M elements
    float* rbuf = ws;
    float* wdec = ws + 1 * M4;
    float* kf   = ws + 2 * M4;
    float* vf   = ws + 3 * M4;
    float* aab  = ws + 4 * M4;
    float* bbb  = ws + 5 * M4;
    float* ybuf = ws + 6 * M4;
    // aliases inside ybuf region (dead before ybuf is written):
    float* kp = ws + 6 * M4;
    float* vp = kp + (size_t)NROWS * 256;
    float* hw = vp + (size_t)NROWS * 256;
    float* ha = hw + (size_t)NROWS * 64;
    float* hv = ha + (size_t)NROWS * 64;
    // alias aab (dead after wkv7):
    float* yn = aab;

    dim3 blk(256);
    gemm_nt<<<dim3(16, 64), blk, 0, stream>>>(x, Wr, rbuf, NROWS, 1024, 1024);
    gemm_nt<<<dim3(4, 64),  blk, 0, stream>>>(x, Wk, kp,   NROWS,  256, 1024);
    gemm_nt<<<dim3(4, 64),  blk, 0, stream>>>(x, Wv, vp,   NROWS,  256, 1024);
    hidden_proj<<<NROWS, blk, 0, stream>>>(x, w1, a1, v1, hw, ha, hv);
    fuse_pre<<<NROWS, blk, 0, stream>>>(kp, vp, hw, ha, hv, v_first, mask,
                                        w0, w2, a0, a2, v0, v2, k_k, k_a,
                                        wdec, kf, vf, aab, bbb);
    wkv7<<<64, blk, 0, stream>>>(rbuf, wdec, kf, vf, aab, bbb, ybuf);
    fuse_post<<<NROWS, blk, 0, stream>>>(ybuf, rbuf, kf, vf, r_k, ln_g, ln_b, yn);
    gemm_nt<<<dim3(16, 64), blk, 0, stream>>>(yn, Wo, out, NROWS, 1024, 1024);
    hipMemcpyAsync(out + M4, v_first, M4 * sizeof(float),
                   hipMemcpyDeviceToDevice, stream);
}

// Round 4
// 1199.690 us; speedup vs baseline: 2.2634x; 1.2191x over previous
//
#include <hip/hip_runtime.h>

// RWKV-7 Tmix (B=4, T=1024, C=1024, H=16, HS=64, H_KV=4)
// Round 3: wkv7 re-parallelized — one wave per (b,h,value-row i): 4096
// independent waves, no barriers, lane j owns S[i][j], shfl-butterfly
// reduces, depth-2 register prefetch. 16 waves/CU for latency hiding.

#define NROWS 4096      // B*T
#define CCH   1024
#define EPSV  0.00064f

// ---------------------------------------------------------------------------
// Tiled f32 GEMM, C[M,N] = A[M,K] * B[N,K]^T.
// BM=BN=64, BK=16, 256 threads, 4x4 per thread.
// ---------------------------------------------------------------------------
__global__ __launch_bounds__(256) void gemm_nt(
    const float* __restrict__ Ap, const float* __restrict__ Bp,
    float* __restrict__ Cp, int M, int N, int K)
{
    __shared__ __align__(16) float As[16][68];
    __shared__ __align__(16) float Bs[16][68];
    const int t  = threadIdx.x;
    const int tx = t & 15, ty = t >> 4;
    const int m0 = blockIdx.y * 64, n0 = blockIdx.x * 64;
    const int lr = t >> 2, lq = t & 3;

    float acc[4][4] = {};

    for (int k0 = 0; k0 < K; k0 += 16) {
        const float4 av = *reinterpret_cast<const float4*>(
            Ap + (size_t)(m0 + lr) * K + k0 + lq * 4);
        const float4 bv = *reinterpret_cast<const float4*>(
            Bp + (size_t)(n0 + lr) * K + k0 + lq * 4);

        As[lq * 4 + 0][lr] = av.x; As[lq * 4 + 1][lr] = av.y;
        As[lq * 4 + 2][lr] = av.z; As[lq * 4 + 3][lr] = av.w;
        Bs[lq * 4 + 0][lr] = bv.x; Bs[lq * 4 + 1][lr] = bv.y;
        Bs[lq * 4 + 2][lr] = bv.z; Bs[lq * 4 + 3][lr] = bv.w;
        __syncthreads();

        #pragma unroll
        for (int kk = 0; kk < 16; ++kk) {
            const float4 a = *reinterpret_cast<const float4*>(&As[kk][ty * 4]);
            const float4 b = *reinterpret_cast<const float4*>(&Bs[kk][tx * 4]);
            acc[0][0] += a.x * b.x; acc[0][1] += a.x * b.y; acc[0][2] += a.x * b.z; acc[0][3] += a.x * b.w;
            acc[1][0] += a.y * b.x; acc[1][1] += a.y * b.y; acc[1][2] += a.y * b.z; acc[1][3] += a.y * b.w;
            acc[2][0] += a.z * b.x; acc[2][1] += a.z * b.y; acc[2][2] += a.z * b.z; acc[2][3] += a.z * b.w;
            acc[3][0] += a.w * b.x; acc[3][1] += a.w * b.y; acc[3][2] += a.w * b.z; acc[3][3] += a.w * b.w;
        }
        __syncthreads();
    }

    #pragma unroll
    for (int i = 0; i < 4; ++i) {
        const size_t row = (size_t)(m0 + ty * 4 + i) * N + n0 + tx * 4;
        *reinterpret_cast<float4*>(Cp + row) =
            make_float4(acc[i][0], acc[i][1], acc[i][2], acc[i][3]);
    }
}

// ---------------------------------------------------------------------------
// Hidden projections: hw = tanh(x@w1) (64), ha = x@a1 (64), hv = x@v1 (32)
// ---------------------------------------------------------------------------
__global__ __launch_bounds__(256) void hidden_proj(
    const float* __restrict__ x, const float* __restrict__ w1,
    const float* __restrict__ a1, const float* __restrict__ v1,
    float* __restrict__ hw, float* __restrict__ ha, float* __restrict__ hv)
{
    const int n = blockIdx.x, t = threadIdx.x;
    __shared__ __align__(16) float xs[1024];
    *reinterpret_cast<float4*>(&xs[t * 4]) =
        *reinterpret_cast<const float4*>(x + (size_t)n * 1024 + t * 4);
    __syncthreads();
    const int w = t >> 6, f = t & 63;
    float acc = 0.f;
    if (w == 0) {
        #pragma unroll 8
        for (int c = 0; c < 1024; ++c) acc += xs[c] * w1[c * 64 + f];
        hw[n * 64 + f] = tanhf(acc);
    } else if (w == 1) {
        #pragma unroll 8
        for (int c = 0; c < 1024; ++c) acc += xs[c] * a1[c * 64 + f];
        ha[n * 64 + f] = acc;
    } else if (w == 2 && f < 32) {
        #pragma unroll 8
        for (int c = 0; c < 1024; ++c) acc += xs[c] * v1[c * 32 + f];
        hv[n * 32 + f] = acc;
    }
}

// ---------------------------------------------------------------------------
// Fused pre-recurrence elementwise. Mask applied HERE (wkv7 reads clean
// streams): k,v,aa,bb *= m ; d = (m>0 ? d : 1).
// ---------------------------------------------------------------------------
__global__ __launch_bounds__(256) void fuse_pre(
    const float* __restrict__ kp, const float* __restrict__ vp,
    const float* __restrict__ hw, const float* __restrict__ ha, const float* __restrict__ hv,
    const float* __restrict__ v_first, const float* __restrict__ mask,
    const float* __restrict__ w0, const float* __restrict__ w2,
    const float* __restrict__ a0, const float* __restrict__ a2,
    const float* __restrict__ v0, const float* __restrict__ v2,
    const float* __restrict__ k_k, const float* __restrict__ k_a,
    float* __restrict__ wdec, float* __restrict__ kf, float* __restrict__ vf,
    float* __restrict__ aab, float* __restrict__ bbb)
{
    const int n = blockIdx.x, t = threadIdx.x;
    __shared__ float shw[64], sha[64], shv[32];
    if (t < 64) shw[t] = hw[n * 64 + t];
    else if (t < 128) sha[t - 64] = ha[n * 64 + t - 64];
    else if (t < 160) shv[t - 128] = hv[n * 32 + t - 128];
    __syncthreads();

    const float m = mask[n];
    const bool live = m > 0.f;

    #pragma unroll
    for (int q = 0; q < 4; ++q) {
        const int c = q * 256 + t;
        // decay: w = -softplus(-dd) - 0.6 ; dec = exp(-exp(w))
        float dd = w0[c];
        #pragma unroll 8
        for (int d = 0; d < 64; ++d) dd += shw[d] * w2[d * 1024 + c];
        const float u  = -dd;
        const float sp = fmaxf(u, 0.f) + log1pf(expf(-fabsf(u)));   // softplus(-dd)
        const float dec = expf(-expf(-sp - 0.6f));
        // a (in-context lr)
        float aacc = a0[c];
        #pragma unroll 8
        for (int d = 0; d < 64; ++d) aacc += sha[d] * a2[d * 1024 + c];
        const float av = 1.f / (1.f + expf(-aacc));
        // v residual-mix gate
        float vacc = v0[c];
        #pragma unroll 8
        for (int d = 0; d < 32; ++d) vacc += shv[d] * v2[d * 1024 + c];
        const float sv = 1.f / (1.f + expf(-vacc));

        // GQA repeat: channel c -> kv channel (c>>8)*64 + (c&63)
        const int  ck  = q * 64 + (c & 63);
        const float kr = kp[(size_t)n * 256 + ck];
        const float vr = vp[(size_t)n * 256 + ck];
        const float vfi = v_first[(size_t)n * 1024 + c];
        const float vv  = vr + (vfi - vr) * sv;

        // kk = normalize_per_head(k * k_k); wave == one head
        const float tkk = kr * k_k[c];
        float ss = tkk * tkk;
        #pragma unroll
        for (int off = 32; off > 0; off >>= 1) ss += __shfl_xor(ss, off, 64);
        const float kkv = tkk / fmaxf(sqrtf(ss), 1e-12f);

        const size_t idx = (size_t)n * 1024 + c;
        wdec[idx] = live ? dec : 1.f;
        kf[idx]   = kr * (1.f + (av - 1.f) * k_a[c]) * m;
        vf[idx]   = vv * m;
        aab[idx]  = -kkv * m;
        bbb[idx]  = kkv * av * m;
    }
}

// ---------------------------------------------------------------------------
// WKV7 recurrence, wave-per-row. Grid: 1024 blocks x 256 thr = 4096 waves.
// Wave (bh, i): lane j holds S[i][j]. No LDS, no barriers. Two shfl
// butterflies per step (sa, y). Depth-2 register prefetch of the 5 streams.
// ---------------------------------------------------------------------------
__device__ __forceinline__ float wred(float x) {
    x += __shfl_xor(x, 32, 64);
    x += __shfl_xor(x, 16, 64);
    x += __shfl_xor(x, 8, 64);
    x += __shfl_xor(x, 4, 64);
    x += __shfl_xor(x, 2, 64);
    x += __shfl_xor(x, 1, 64);
    return x;
}

__global__ __launch_bounds__(256) void wkv7(
    const float* __restrict__ r, const float* __restrict__ wdec,
    const float* __restrict__ kf, const float* __restrict__ vf,
    const float* __restrict__ aab, const float* __restrict__ bbb,
    float* __restrict__ y)
{
    const int blk = blockIdx.x;              // 1024
    const int bh  = blk >> 4;                // 0..63
    const int b   = bh >> 4, h = bh & 15;
    const int i   = ((blk & 15) << 2) | (threadIdx.x >> 6);  // row 0..63
    const int lane = threadIdx.x & 63;
    const size_t cb = (size_t)b * (1024 * 1024) + (size_t)h * 64;

    float S = 0.f;

    float dA, kA, aA, bA, rA, vA;
    float dB, kB, aB, bB, rB, vB;

    auto ld = [&](int t, float& dd, float& kk, float& aa, float& bb,
                  float& rr, float& vv) {
        const size_t p = cb + (size_t)t * 1024;
        dd = wdec[p + lane]; kk = kf[p + lane]; aa = aab[p + lane];
        bb = bbb[p + lane];  rr = r[p + lane];  vv = vf[p + i];
    };

    ld(0, dA, kA, aA, bA, rA, vA);
    ld(1, dB, kB, aB, bB, rB, vB);

    for (int t = 0; t < 1024; t += 2) {
        {
            const float sa = wred(S * aA);
            S = S * dA + sa * bA + vA * kA;
            const float yv = wred(S * rA);
            if (lane == 0) y[cb + (size_t)t * 1024 + i] = yv;
        }
        if (t + 2 < 1024) ld(t + 2, dA, kA, aA, bA, rA, vA);
        {
            const float sa = wred(S * aB);
            S = S * dB + sa * bB + vB * kB;
            const float yv = wred(S * rB);
            if (lane == 0) y[cb + (size_t)(t + 1) * 1024 + i] = yv;
        }
        if (t + 3 < 1024) ld(t + 3, dB, kB, aB, bB, rB, vB);
    }
}

// ---------------------------------------------------------------------------
// Post: groupnorm per (row, head) + rk*v residual
// ---------------------------------------------------------------------------
__global__ __launch_bounds__(256) void fuse_post(
    const float* __restrict__ y, const float* __restrict__ r,
    const float* __restrict__ kf, const float* __restrict__ vf,
    const float* __restrict__ r_k, const float* __restrict__ ln_g, const float* __restrict__ ln_b,
    float* __restrict__ yn)
{
    const int n = blockIdx.x, t = threadIdx.x;
    #pragma unroll
    for (int q = 0; q < 4; ++q) {
        const int c = q * 256 + t;
        const size_t idx = (size_t)n * 1024 + c;
        const float yv = y[idx];
        float s1 = yv, s2 = yv * yv;
        float rk = r[idx] * kf[idx] * r_k[c];
        #pragma unroll
        for (int off = 32; off > 0; off >>= 1) {
            s1 += __shfl_xor(s1, off, 64);
            s2 += __shfl_xor(s2, off, 64);
            rk += __shfl_xor(rk, off, 64);
        }
        const float mu  = s1 * (1.f / 64.f);
        const float var = s2 * (1.f / 64.f) - mu * mu;
        yn[idx] = (yv - mu) * rsqrtf(var + EPSV) * ln_g[c] + ln_b[c]
                  + rk * vf[idx];
    }
}

// ---------------------------------------------------------------------------
extern "C" void kernel_launch(void* const* d_in, const int* in_sizes, int n_in,
                              void* d_out, int out_size, void* d_ws, size_t ws_size,
                              hipStream_t stream)
{
    const float* x       = (const float*)d_in[0];
    const float* v_first = (const float*)d_in[1];
    const float* mask    = (const float*)d_in[2];
    const float* Wr      = (const float*)d_in[3];
    const float* Wk      = (const float*)d_in[4];
    const float* Wv      = (const float*)d_in[5];
    const float* Wo      = (const float*)d_in[6];
    const float* w0      = (const float*)d_in[7];
    const float* w1      = (const float*)d_in[8];
    const float* w2      = (const float*)d_in[9];
    const float* a0      = (const float*)d_in[10];
    const float* a1      = (const float*)d_in[11];
    const float* a2      = (const float*)d_in[12];
    const float* v0      = (const float*)d_in[13];
    const float* v1      = (const float*)d_in[14];
    const float* v2      = (const float*)d_in[15];
    const float* k_k     = (const float*)d_in[16];
    const float* k_a     = (const float*)d_in[17];
    const float* r_k     = (const float*)d_in[18];
    const float* ln_g    = (const float*)d_in[19];
    const float* ln_b    = (const float*)d_in[20];
    float* out = (float*)d_out;

    float* ws = (float*)d_ws;
    const size_t M4 = (size_t)NROWS * CCH;   // 4M elements
    float* rbuf = ws;
    float* wdec = ws + 1 * M4;
    float* kf   = ws + 2 * M4;
    float* vf   = ws + 3 * M4;
    float* aab  = ws + 4 * M4;
    float* bbb  = ws + 5 * M4;
    float* ybuf = ws + 6 * M4;
    // aliases inside ybuf region (dead before ybuf is written):
    float* kp = ws + 6 * M4;
    float* vp = kp + (size_t)NROWS * 256;
    float* hw = vp + (size_t)NROWS * 256;
    float* ha = hw + (size_t)NROWS * 64;
    float* hv = ha + (size_t)NROWS * 64;
    // alias aab (dead after wkv7):
    float* yn = aab;

    dim3 blk(256);
    gemm_nt<<<dim3(16, 64), blk, 0, stream>>>(x, Wr, rbuf, NROWS, 1024, 1024);
    gemm_nt<<<dim3(4, 64),  blk, 0, stream>>>(x, Wk, kp,   NROWS,  256, 1024);
    gemm_nt<<<dim3(4, 64),  blk, 0, stream>>>(x, Wv, vp,   NROWS,  256, 1024);
    hidden_proj<<<NROWS, blk, 0, stream>>>(x, w1, a1, v1, hw, ha, hv);
    fuse_pre<<<NROWS, blk, 0, stream>>>(kp, vp, hw, ha, hv, v_first, mask,
                                        w0, w2, a0, a2, v0, v2, k_k, k_a,
                                        wdec, kf, vf, aab, bbb);
    wkv7<<<1024, blk, 0, stream>>>(rbuf, wdec, kf, vf, aab, bbb, ybuf);
    fuse_post<<<NROWS, blk, 0, stream>>>(ybuf, rbuf, kf, vf, r_k, ln_g, ln_b, yn);
    gemm_nt<<<dim3(16, 64), blk, 0, stream>>>(yn, Wo, out, NROWS, 1024, 1024);
    hipMemcpyAsync(out + M4, v_first, M4 * sizeof(float),
                   hipMemcpyDeviceToDevice, stream);
}

// Round 6
// 990.128 us; speedup vs baseline: 2.7424x; 1.2117x over previous
//
#include <hip/hip_runtime.h>

// RWKV-7 Tmix (B=4, T=1024, C=1024, H=16, HS=64, H_KV=4)
// Round 5: split-precision bf16 MFMA (hi+lo, 3 passes) for r/kv GEMMs
// (recurrence-amplified paths need ~f32 precision); plain bf16 MFMA for the
// output GEMM (no amplification). wkv7 = R4's 2-rows/wave version.

#define NROWS 4096      // B*T
#define CCH   1024
#define EPSV  0.00064f

typedef __attribute__((ext_vector_type(4))) float f32x4;
typedef __attribute__((ext_vector_type(8))) short bf16x8;

__device__ __forceinline__ unsigned short f2b(float f) {
    unsigned x = __float_as_uint(f);
    return (unsigned short)((x + 0x7fffu + ((x >> 16) & 1u)) >> 16);
}
__device__ __forceinline__ float b2f(unsigned short u) {
    return __uint_as_float(((unsigned)u) << 16);
}

#define LDSTR 40

// ---------------------------------------------------------------------------
// Split-precision MFMA GEMM: C[M,N] = A[M,K]*B[N,K]^T, A,B,C f32.
// A,B decomposed to bf16 hi+lo; C += Ahi*Bhi + Ahi*Blo + Alo*Bhi.
// BM=BN=128, BK=32, 256 thr = 4 waves (2x2 of 64x64), 48 MFMA/K-step.
// ---------------------------------------------------------------------------
__global__ __launch_bounds__(256) void gemm_split(
    const float* __restrict__ A, const float* __restrict__ B,
    float* __restrict__ C, int M, int N, int K)
{
    __shared__ __align__(16) unsigned short Ah[128 * LDSTR];
    __shared__ __align__(16) unsigned short Al[128 * LDSTR];
    __shared__ __align__(16) unsigned short Bh[128 * LDSTR];
    __shared__ __align__(16) unsigned short Bl[128 * LDSTR];
    const int t = threadIdx.x;
    const int wave = t >> 6, lane = t & 63;
    const int m0 = blockIdx.y * 128, n0 = blockIdx.x * 128;
    const int wm = (wave >> 1) * 64, wn = (wave & 1) * 64;
    const int fr = lane & 15, kq = lane >> 4;

    f32x4 acc[4][4];
    #pragma unroll
    for (int i = 0; i < 4; ++i)
        #pragma unroll
        for (int j = 0; j < 4; ++j)
            acc[i][j] = (f32x4){0.f, 0.f, 0.f, 0.f};

    const int srow = t >> 3;         // 0..31
    const int scol = (t & 7) * 4;    // 0,4,..,28

    for (int k0 = 0; k0 < K; k0 += 32) {
        #pragma unroll
        for (int p = 0; p < 4; ++p) {
            const int row = p * 32 + srow;
            {
                const float4 v = *reinterpret_cast<const float4*>(
                    A + (size_t)(m0 + row) * K + k0 + scol);
                ushort4 h, l;
                h.x = f2b(v.x); l.x = f2b(v.x - b2f(h.x));
                h.y = f2b(v.y); l.y = f2b(v.y - b2f(h.y));
                h.z = f2b(v.z); l.z = f2b(v.z - b2f(h.z));
                h.w = f2b(v.w); l.w = f2b(v.w - b2f(h.w));
                *reinterpret_cast<ushort4*>(&Ah[row * LDSTR + scol]) = h;
                *reinterpret_cast<ushort4*>(&Al[row * LDSTR + scol]) = l;
            }
            {
                float4 v = make_float4(0.f, 0.f, 0.f, 0.f);
                if (n0 + row < N)
                    v = *reinterpret_cast<const float4*>(
                        B + (size_t)(n0 + row) * K + k0 + scol);
                ushort4 h, l;
                h.x = f2b(v.x); l.x = f2b(v.x - b2f(h.x));
                h.y = f2b(v.y); l.y = f2b(v.y - b2f(h.y));
                h.z = f2b(v.z); l.z = f2b(v.z - b2f(h.z));
                h.w = f2b(v.w); l.w = f2b(v.w - b2f(h.w));
                *reinterpret_cast<ushort4*>(&Bh[row * LDSTR + scol]) = h;
                *reinterpret_cast<ushort4*>(&Bl[row * LDSTR + scol]) = l;
            }
        }
        __syncthreads();

        bf16x8 ah[4], al[4], bh[4], bl[4];
        #pragma unroll
        for (int mi = 0; mi < 4; ++mi) {
            ah[mi] = *reinterpret_cast<const bf16x8*>(&Ah[(wm + mi * 16 + fr) * LDSTR + kq * 8]);
            al[mi] = *reinterpret_cast<const bf16x8*>(&Al[(wm + mi * 16 + fr) * LDSTR + kq * 8]);
        }
        #pragma unroll
        for (int ni = 0; ni < 4; ++ni) {
            bh[ni] = *reinterpret_cast<const bf16x8*>(&Bh[(wn + ni * 16 + fr) * LDSTR + kq * 8]);
            bl[ni] = *reinterpret_cast<const bf16x8*>(&Bl[(wn + ni * 16 + fr) * LDSTR + kq * 8]);
        }
        #pragma unroll
        for (int mi = 0; mi < 4; ++mi)
            #pragma unroll
            for (int ni = 0; ni < 4; ++ni) {
                acc[mi][ni] = __builtin_amdgcn_mfma_f32_16x16x32_bf16(
                    al[mi], bh[ni], acc[mi][ni], 0, 0, 0);
                acc[mi][ni] = __builtin_amdgcn_mfma_f32_16x16x32_bf16(
                    ah[mi], bl[ni], acc[mi][ni], 0, 0, 0);
                acc[mi][ni] = __builtin_amdgcn_mfma_f32_16x16x32_bf16(
                    ah[mi], bh[ni], acc[mi][ni], 0, 0, 0);
            }
        __syncthreads();
    }

    // C/D: col = lane&15, row = (lane>>4)*4 + reg
    const int crow0 = m0 + wm + kq * 4;
    const int ccol0 = n0 + wn + fr;
    #pragma unroll
    for (int mi = 0; mi < 4; ++mi)
        #pragma unroll
        for (int ni = 0; ni < 4; ++ni) {
            const int col = ccol0 + ni * 16;
            if (col < N) {
                #pragma unroll
                for (int i = 0; i < 4; ++i)
                    C[(size_t)(crow0 + mi * 16 + i) * N + col] = acc[mi][ni][i];
            }
        }
}

// ---------------------------------------------------------------------------
// Plain bf16 MFMA GEMM (output projection — no error amplification).
// ---------------------------------------------------------------------------
__global__ __launch_bounds__(256) void gemm_mfma(
    const float* __restrict__ A, const float* __restrict__ B,
    float* __restrict__ C, int M, int N, int K)
{
    __shared__ __align__(16) unsigned short Ah[128 * LDSTR];
    __shared__ __align__(16) unsigned short Bh[128 * LDSTR];
    const int t = threadIdx.x;
    const int wave = t >> 6, lane = t & 63;
    const int m0 = blockIdx.y * 128, n0 = blockIdx.x * 128;
    const int wm = (wave >> 1) * 64, wn = (wave & 1) * 64;
    const int fr = lane & 15, kq = lane >> 4;

    f32x4 acc[4][4];
    #pragma unroll
    for (int i = 0; i < 4; ++i)
        #pragma unroll
        for (int j = 0; j < 4; ++j)
            acc[i][j] = (f32x4){0.f, 0.f, 0.f, 0.f};

    const int srow = t >> 3;
    const int scol = (t & 7) * 4;

    for (int k0 = 0; k0 < K; k0 += 32) {
        #pragma unroll
        for (int p = 0; p < 4; ++p) {
            const int row = p * 32 + srow;
            const float4 av = *reinterpret_cast<const float4*>(
                A + (size_t)(m0 + row) * K + k0 + scol);
            ushort4 a4;
            a4.x = f2b(av.x); a4.y = f2b(av.y); a4.z = f2b(av.z); a4.w = f2b(av.w);
            *reinterpret_cast<ushort4*>(&Ah[row * LDSTR + scol]) = a4;
            const float4 bv = *reinterpret_cast<const float4*>(
                B + (size_t)(n0 + row) * K + k0 + scol);
            ushort4 b4;
            b4.x = f2b(bv.x); b4.y = f2b(bv.y); b4.z = f2b(bv.z); b4.w = f2b(bv.w);
            *reinterpret_cast<ushort4*>(&Bh[row * LDSTR + scol]) = b4;
        }
        __syncthreads();

        bf16x8 af[4], bfr[4];
        #pragma unroll
        for (int mi = 0; mi < 4; ++mi)
            af[mi] = *reinterpret_cast<const bf16x8*>(&Ah[(wm + mi * 16 + fr) * LDSTR + kq * 8]);
        #pragma unroll
        for (int ni = 0; ni < 4; ++ni)
            bfr[ni] = *reinterpret_cast<const bf16x8*>(&Bh[(wn + ni * 16 + fr) * LDSTR + kq * 8]);
        #pragma unroll
        for (int mi = 0; mi < 4; ++mi)
            #pragma unroll
            for (int ni = 0; ni < 4; ++ni)
                acc[mi][ni] = __builtin_amdgcn_mfma_f32_16x16x32_bf16(
                    af[mi], bfr[ni], acc[mi][ni], 0, 0, 0);
        __syncthreads();
    }

    const int crow0 = m0 + wm + kq * 4;
    const int ccol0 = n0 + wn + fr;
    #pragma unroll
    for (int mi = 0; mi < 4; ++mi)
        #pragma unroll
        for (int ni = 0; ni < 4; ++ni) {
            const int col = ccol0 + ni * 16;
            #pragma unroll
            for (int i = 0; i < 4; ++i)
                C[(size_t)(crow0 + mi * 16 + i) * N + col] = acc[mi][ni][i];
        }
}

// ---------------------------------------------------------------------------
// Pack Wk,Wv into one [512][1024] weight (so k,v are one GEMM).
// ---------------------------------------------------------------------------
__global__ __launch_bounds__(256) void pack_kv(
    const float* __restrict__ Wk, const float* __restrict__ Wv,
    float* __restrict__ W)
{
    const int row = blockIdx.x;  // 0..511
    const float* s = row < 256 ? Wk + (size_t)row * 1024
                               : Wv + (size_t)(row - 256) * 1024;
    const float4 v = *reinterpret_cast<const float4*>(s + threadIdx.x * 4);
    *reinterpret_cast<float4*>(W + (size_t)row * 1024 + threadIdx.x * 4) = v;
}

// ---------------------------------------------------------------------------
// Hidden projections: hw = tanh(x@w1) (64), ha = x@a1 (64), hv = x@v1 (32)
// ---------------------------------------------------------------------------
__global__ __launch_bounds__(256) void hidden_proj(
    const float* __restrict__ x, const float* __restrict__ w1,
    const float* __restrict__ a1, const float* __restrict__ v1,
    float* __restrict__ hw, float* __restrict__ ha, float* __restrict__ hv)
{
    const int n = blockIdx.x, t = threadIdx.x;
    __shared__ __align__(16) float xs[1024];
    *reinterpret_cast<float4*>(&xs[t * 4]) =
        *reinterpret_cast<const float4*>(x + (size_t)n * 1024 + t * 4);
    __syncthreads();
    const int w = t >> 6, f = t & 63;
    float acc = 0.f;
    if (w == 0) {
        #pragma unroll 8
        for (int c = 0; c < 1024; ++c) acc += xs[c] * w1[c * 64 + f];
        hw[n * 64 + f] = tanhf(acc);
    } else if (w == 1) {
        #pragma unroll 8
        for (int c = 0; c < 1024; ++c) acc += xs[c] * a1[c * 64 + f];
        ha[n * 64 + f] = acc;
    } else if (w == 2 && f < 32) {
        #pragma unroll 8
        for (int c = 0; c < 1024; ++c) acc += xs[c] * v1[c * 32 + f];
        hv[n * 32 + f] = acc;
    }
}

// ---------------------------------------------------------------------------
// Fused pre-recurrence elementwise. Mask applied HERE.
// kv layout: [4096][512] — k in cols 0..255, v in cols 256..511.
// ---------------------------------------------------------------------------
__global__ __launch_bounds__(256) void fuse_pre(
    const float* __restrict__ kv,
    const float* __restrict__ hw, const float* __restrict__ ha, const float* __restrict__ hv,
    const float* __restrict__ v_first, const float* __restrict__ mask,
    const float* __restrict__ w0, const float* __restrict__ w2,
    const float* __restrict__ a0, const float* __restrict__ a2,
    const float* __restrict__ v0, const float* __restrict__ v2,
    const float* __restrict__ k_k, const float* __restrict__ k_a,
    float* __restrict__ wdec, float* __restrict__ kf, float* __restrict__ vf,
    float* __restrict__ aab, float* __restrict__ bbb)
{
    const int n = blockIdx.x, t = threadIdx.x;
    __shared__ float shw[64], sha[64], shv[32];
    if (t < 64) shw[t] = hw[n * 64 + t];
    else if (t < 128) sha[t - 64] = ha[n * 64 + t - 64];
    else if (t < 160) shv[t - 128] = hv[n * 32 + t - 128];
    __syncthreads();

    const float m = mask[n];
    const bool live = m > 0.f;

    #pragma unroll
    for (int q = 0; q < 4; ++q) {
        const int c = q * 256 + t;
        float dd = w0[c];
        #pragma unroll 8
        for (int d = 0; d < 64; ++d) dd += shw[d] * w2[d * 1024 + c];
        const float u  = -dd;
        const float sp = fmaxf(u, 0.f) + log1pf(expf(-fabsf(u)));
        const float dec = expf(-expf(-sp - 0.6f));
        float aacc = a0[c];
        #pragma unroll 8
        for (int d = 0; d < 64; ++d) aacc += sha[d] * a2[d * 1024 + c];
        const float av = 1.f / (1.f + expf(-aacc));
        float vacc = v0[c];
        #pragma unroll 8
        for (int d = 0; d < 32; ++d) vacc += shv[d] * v2[d * 1024 + c];
        const float sv = 1.f / (1.f + expf(-vacc));

        const int  ck  = q * 64 + (c & 63);
        const float kr = kv[(size_t)n * 512 + ck];
        const float vr = kv[(size_t)n * 512 + 256 + ck];
        const float vfi = v_first[(size_t)n * 1024 + c];
        const float vv  = vr + (vfi - vr) * sv;

        const float tkk = kr * k_k[c];
        float ss = tkk * tkk;
        #pragma unroll
        for (int off = 32; off > 0; off >>= 1) ss += __shfl_xor(ss, off, 64);
        const float kkv = tkk / fmaxf(sqrtf(ss), 1e-12f);

        const size_t idx = (size_t)n * 1024 + c;
        wdec[idx] = live ? dec : 1.f;
        kf[idx]   = kr * (1.f + (av - 1.f) * k_a[c]) * m;
        vf[idx]   = vv * m;
        aab[idx]  = -kkv * m;
        bbb[idx]  = kkv * av * m;
    }
}

// ---------------------------------------------------------------------------
// WKV7: 512 blocks x 4 waves = 2048 waves; wave = (bh, row-pair).
// Lane l: half = l>>5, row i = 2*wib+half, channels 2*(l&31), 2*(l&31)+1.
// Reduces: 5-deep within-32 butterflies. Depth-2 float2 prefetch.
// ---------------------------------------------------------------------------
__global__ __launch_bounds__(256) void wkv7(
    const float* __restrict__ r, const float* __restrict__ wdec,
    const float* __restrict__ kf, const float* __restrict__ vf,
    const float* __restrict__ aab, const float* __restrict__ bbb,
    float* __restrict__ y)
{
    const int blk = blockIdx.x;              // 0..511
    const int bh  = blk >> 3;                // 0..63
    const int b   = bh >> 4, h = bh & 15;
    const int wib = ((blk & 7) << 2) | (threadIdx.x >> 6);   // 0..31
    const int lane = threadIdx.x & 63;
    const int half = lane >> 5;
    const int jl   = lane & 31;
    const int c0   = jl * 2;
    const int i    = wib * 2 + half;
    const size_t cb = (size_t)b * (1024 * 1024) + (size_t)h * 64;

    float S0 = 0.f, S1 = 0.f;

    float2 dA, kA, aA, bA, rA; float vA;
    float2 dB, kB, aB, bB, rB; float vB;

    auto ld = [&](int t, float2& dv, float2& kv2, float2& av, float2& bv,
                  float2& rv, float& vv) {
        const size_t p = cb + (size_t)t * 1024;
        dv  = *reinterpret_cast<const float2*>(wdec + p + c0);
        kv2 = *reinterpret_cast<const float2*>(kf + p + c0);
        av  = *reinterpret_cast<const float2*>(aab + p + c0);
        bv  = *reinterpret_cast<const float2*>(bbb + p + c0);
        rv  = *reinterpret_cast<const float2*>(r + p + c0);
        vv  = vf[p + i];
    };

    ld(0, dA, kA, aA, bA, rA, vA);
    ld(1, dB, kB, aB, bB, rB, vB);

    for (int t = 0; t < 1024; t += 2) {
        {
            float sa = S0 * aA.x + S1 * aA.y;
            sa += __shfl_xor(sa, 16, 32); sa += __shfl_xor(sa, 8, 32);
            sa += __shfl_xor(sa, 4, 32);  sa += __shfl_xor(sa, 2, 32);
            sa += __shfl_xor(sa, 1, 32);
            S0 = S0 * dA.x + sa * bA.x + vA * kA.x;
            S1 = S1 * dA.y + sa * bA.y + vA * kA.y;
            float yv = S0 * rA.x + S1 * rA.y;
            yv += __shfl_xor(yv, 16, 32); yv += __shfl_xor(yv, 8, 32);
            yv += __shfl_xor(yv, 4, 32);  yv += __shfl_xor(yv, 2, 32);
            yv += __shfl_xor(yv, 1, 32);
            if (jl == 0) y[cb + (size_t)t * 1024 + i] = yv;
        }
        if (t + 2 < 1024) ld(t + 2, dA, kA, aA, bA, rA, vA);
        {
            float sa = S0 * aB.x + S1 * aB.y;
            sa += __shfl_xor(sa, 16, 32); sa += __shfl_xor(sa, 8, 32);
            sa += __shfl_xor(sa, 4, 32);  sa += __shfl_xor(sa, 2, 32);
            sa += __shfl_xor(sa, 1, 32);
            S0 = S0 * dB.x + sa * bB.x + vB * kB.x;
            S1 = S1 * dB.y + sa * bB.y + vB * kB.y;
            float yv = S0 * rB.x + S1 * rB.y;
            yv += __shfl_xor(yv, 16, 32); yv += __shfl_xor(yv, 8, 32);
            yv += __shfl_xor(yv, 4, 32);  yv += __shfl_xor(yv, 2, 32);
            yv += __shfl_xor(yv, 1, 32);
            if (jl == 0) y[cb + (size_t)(t + 1) * 1024 + i] = yv;
        }
        if (t + 3 < 1024) ld(t + 3, dB, kB, aB, bB, rB, vB);
    }
}

// ---------------------------------------------------------------------------
// Post: groupnorm per (row, head) + rk*v residual
// ---------------------------------------------------------------------------
__global__ __launch_bounds__(256) void fuse_post(
    const float* __restrict__ y, const float* __restrict__ r,
    const float* __restrict__ kf, const float* __restrict__ vf,
    const float* __restrict__ r_k, const float* __restrict__ ln_g, const float* __restrict__ ln_b,
    float* __restrict__ yn)
{
    const int n = blockIdx.x, t = threadIdx.x;
    #pragma unroll
    for (int q = 0; q < 4; ++q) {
        const int c = q * 256 + t;
        const size_t idx = (size_t)n * 1024 + c;
        const float yv = y[idx];
        float s1 = yv, s2 = yv * yv;
        float rk = r[idx] * kf[idx] * r_k[c];
        #pragma unroll
        for (int off = 32; off > 0; off >>= 1) {
            s1 += __shfl_xor(s1, off, 64);
            s2 += __shfl_xor(s2, off, 64);
            rk += __shfl_xor(rk, off, 64);
        }
        const float mu  = s1 * (1.f / 64.f);
        const float var = s2 * (1.f / 64.f) - mu * mu;
        yn[idx] = (yv - mu) * rsqrtf(var + EPSV) * ln_g[c] + ln_b[c]
                  + rk * vf[idx];
    }
}

// ---------------------------------------------------------------------------
extern "C" void kernel_launch(void* const* d_in, const int* in_sizes, int n_in,
                              void* d_out, int out_size, void* d_ws, size_t ws_size,
                              hipStream_t stream)
{
    const float* x       = (const float*)d_in[0];
    const float* v_first = (const float*)d_in[1];
    const float* mask    = (const float*)d_in[2];
    const float* Wr      = (const float*)d_in[3];
    const float* Wk      = (const float*)d_in[4];
    const float* Wv      = (const float*)d_in[5];
    const float* Wo      = (const float*)d_in[6];
    const float* w0      = (const float*)d_in[7];
    const float* w1      = (const float*)d_in[8];
    const float* w2      = (const float*)d_in[9];
    const float* a0      = (const float*)d_in[10];
    const float* a1      = (const float*)d_in[11];
    const float* a2      = (const float*)d_in[12];
    const float* v0      = (const float*)d_in[13];
    const float* v1      = (const float*)d_in[14];
    const float* v2      = (const float*)d_in[15];
    const float* k_k     = (const float*)d_in[16];
    const float* k_a     = (const float*)d_in[17];
    const float* r_k     = (const float*)d_in[18];
    const float* ln_g    = (const float*)d_in[19];
    const float* ln_b    = (const float*)d_in[20];
    float* out = (float*)d_out;

    float* ws = (float*)d_ws;
    const size_t M4 = (size_t)NROWS * CCH;   // 4M elements
    float* rbuf = ws;
    float* wdec = ws + 1 * M4;
    float* kf   = ws + 2 * M4;
    float* vf   = ws + 3 * M4;
    float* aab  = ws + 4 * M4;
    float* bbb  = ws + 5 * M4;
    float* ybuf = ws + 6 * M4;
    // aliases inside ybuf region (dead before ybuf is written):
    float* kv   = ws + 6 * M4;                     // [4096][512]
    float* hw   = kv + (size_t)NROWS * 512;        // [4096][64]
    float* ha   = hw + (size_t)NROWS * 64;
    float* hv   = ha + (size_t)NROWS * 64;         // [4096][32]
    float* kvw  = hv + (size_t)NROWS * 32;         // [512][1024] packed weights
    // alias aab (dead after wkv7):
    float* yn = aab;

    dim3 blk(256);
    pack_kv<<<512, blk, 0, stream>>>(Wk, Wv, kvw);
    gemm_split<<<dim3(8, 32), blk, 0, stream>>>(x, Wr, rbuf, NROWS, 1024, 1024);
    gemm_split<<<dim3(4, 32), blk, 0, stream>>>(x, kvw, kv, NROWS, 512, 1024);
    hidden_proj<<<NROWS, blk, 0, stream>>>(x, w1, a1, v1, hw, ha, hv);
    fuse_pre<<<NROWS, blk, 0, stream>>>(kv, hw, ha, hv, v_first, mask,
                                        w0, w2, a0, a2, v0, v2, k_k, k_a,
                                        wdec, kf, vf, aab, bbb);
    wkv7<<<512, blk, 0, stream>>>(rbuf, wdec, kf, vf, aab, bbb, ybuf);
    fuse_post<<<NROWS, blk, 0, stream>>>(ybuf, rbuf, kf, vf, r_k, ln_g, ln_b, yn);
    gemm_mfma<<<dim3(8, 32), blk, 0, stream>>>(yn, Wo, out, NROWS, 1024, 1024);
    hipMemcpyAsync(out + M4, v_first, M4 * sizeof(float),
                   hipMemcpyDeviceToDevice, stream);
}

// Round 7
// 683.361 us; speedup vs baseline: 3.9735x; 1.4489x over previous
//
#include <hip/hip_runtime.h>

// RWKV-7 Tmix (B=4, T=1024, C=1024, H=16, HS=64, H_KV=4)
// Round 6: wkv7 -> 4 rows/wave, 16 lanes/row, float4 channels, DPP-only
// reduces (no DS butterflies), depth-4 prefetch, batched y stores.
// hidden_proj/fuse_pre heavy loops -> split-precision MFMA GEMMs.

#define NROWS 4096      // B*T
#define CCH   1024
#define EPSV  0.00064f

typedef __attribute__((ext_vector_type(4))) float f32x4;
typedef __attribute__((ext_vector_type(8))) short bf16x8;

__device__ __forceinline__ unsigned short f2b(float f) {
    unsigned x = __float_as_uint(f);
    return (unsigned short)((x + 0x7fffu + ((x >> 16) & 1u)) >> 16);
}
__device__ __forceinline__ float b2f(unsigned short u) {
    return __uint_as_float(((unsigned)u) << 16);
}

#define LDSTR 40

// ---------------------------------------------------------------------------
// Split-precision MFMA GEMM: C[M,N] = A[M,K]*B[N,K]^T (f32 in/out).
// A,B -> bf16 hi+lo; C += Ahi*Bhi + Ahi*Blo + Alo*Bhi.
// BM=BN=128, BK=32, 256 thr = 4 waves. TANH64: tanh() on output cols < 64.
// ---------------------------------------------------------------------------
template<bool TANH64>
__global__ __launch_bounds__(256) void gemm_split(
    const float* __restrict__ A, int lda, const float* __restrict__ B, int ldb,
    float* __restrict__ C, int ldc, int M, int N, int K)
{
    __shared__ __align__(16) unsigned short Ah[128 * LDSTR];
    __shared__ __align__(16) unsigned short Al[128 * LDSTR];
    __shared__ __align__(16) unsigned short Bh[128 * LDSTR];
    __shared__ __align__(16) unsigned short Bl[128 * LDSTR];
    const int t = threadIdx.x;
    const int wave = t >> 6, lane = t & 63;
    const int m0 = blockIdx.y * 128, n0 = blockIdx.x * 128;
    const int wm = (wave >> 1) * 64, wn = (wave & 1) * 64;
    const int fr = lane & 15, kq = lane >> 4;

    f32x4 acc[4][4];
    #pragma unroll
    for (int i = 0; i < 4; ++i)
        #pragma unroll
        for (int j = 0; j < 4; ++j)
            acc[i][j] = (f32x4){0.f, 0.f, 0.f, 0.f};

    const int srow = t >> 3;         // 0..31
    const int scol = (t & 7) * 4;    // 0,4,..,28

    for (int k0 = 0; k0 < K; k0 += 32) {
        #pragma unroll
        for (int p = 0; p < 4; ++p) {
            const int row = p * 32 + srow;
            {
                const float4 v = *reinterpret_cast<const float4*>(
                    A + (size_t)(m0 + row) * lda + k0 + scol);
                ushort4 h, l;
                h.x = f2b(v.x); l.x = f2b(v.x - b2f(h.x));
                h.y = f2b(v.y); l.y = f2b(v.y - b2f(h.y));
                h.z = f2b(v.z); l.z = f2b(v.z - b2f(h.z));
                h.w = f2b(v.w); l.w = f2b(v.w - b2f(h.w));
                *reinterpret_cast<ushort4*>(&Ah[row * LDSTR + scol]) = h;
                *reinterpret_cast<ushort4*>(&Al[row * LDSTR + scol]) = l;
            }
            {
                float4 v = make_float4(0.f, 0.f, 0.f, 0.f);
                if (n0 + row < N)
                    v = *reinterpret_cast<const float4*>(
                        B + (size_t)(n0 + row) * ldb + k0 + scol);
                ushort4 h, l;
                h.x = f2b(v.x); l.x = f2b(v.x - b2f(h.x));
                h.y = f2b(v.y); l.y = f2b(v.y - b2f(h.y));
                h.z = f2b(v.z); l.z = f2b(v.z - b2f(h.z));
                h.w = f2b(v.w); l.w = f2b(v.w - b2f(h.w));
                *reinterpret_cast<ushort4*>(&Bh[row * LDSTR + scol]) = h;
                *reinterpret_cast<ushort4*>(&Bl[row * LDSTR + scol]) = l;
            }
        }
        __syncthreads();

        bf16x8 ah[4], al[4], bh[4], bl[4];
        #pragma unroll
        for (int mi = 0; mi < 4; ++mi) {
            ah[mi] = *reinterpret_cast<const bf16x8*>(&Ah[(wm + mi * 16 + fr) * LDSTR + kq * 8]);
            al[mi] = *reinterpret_cast<const bf16x8*>(&Al[(wm + mi * 16 + fr) * LDSTR + kq * 8]);
        }
        #pragma unroll
        for (int ni = 0; ni < 4; ++ni) {
            bh[ni] = *reinterpret_cast<const bf16x8*>(&Bh[(wn + ni * 16 + fr) * LDSTR + kq * 8]);
            bl[ni] = *reinterpret_cast<const bf16x8*>(&Bl[(wn + ni * 16 + fr) * LDSTR + kq * 8]);
        }
        #pragma unroll
        for (int mi = 0; mi < 4; ++mi)
            #pragma unroll
            for (int ni = 0; ni < 4; ++ni) {
                acc[mi][ni] = __builtin_amdgcn_mfma_f32_16x16x32_bf16(
                    al[mi], bh[ni], acc[mi][ni], 0, 0, 0);
                acc[mi][ni] = __builtin_amdgcn_mfma_f32_16x16x32_bf16(
                    ah[mi], bl[ni], acc[mi][ni], 0, 0, 0);
                acc[mi][ni] = __builtin_amdgcn_mfma_f32_16x16x32_bf16(
                    ah[mi], bh[ni], acc[mi][ni], 0, 0, 0);
            }
        __syncthreads();
    }

    const int crow0 = m0 + wm + kq * 4;
    const int ccol0 = n0 + wn + fr;
    #pragma unroll
    for (int mi = 0; mi < 4; ++mi)
        #pragma unroll
        for (int ni = 0; ni < 4; ++ni) {
            const int col = ccol0 + ni * 16;
            if (col < N) {
                #pragma unroll
                for (int i = 0; i < 4; ++i) {
                    float v = acc[mi][ni][i];
                    if (TANH64 && col < 64) v = tanhf(v);
                    C[(size_t)(crow0 + mi * 16 + i) * ldc + col] = v;
                }
            }
        }
}

// ---------------------------------------------------------------------------
// Plain bf16 MFMA GEMM (output projection — no error amplification).
// ---------------------------------------------------------------------------
__global__ __launch_bounds__(256) void gemm_mfma(
    const float* __restrict__ A, const float* __restrict__ B,
    float* __restrict__ C, int M, int N, int K)
{
    __shared__ __align__(16) unsigned short Ah[128 * LDSTR];
    __shared__ __align__(16) unsigned short Bh[128 * LDSTR];
    const int t = threadIdx.x;
    const int wave = t >> 6, lane = t & 63;
    const int m0 = blockIdx.y * 128, n0 = blockIdx.x * 128;
    const int wm = (wave >> 1) * 64, wn = (wave & 1) * 64;
    const int fr = lane & 15, kq = lane >> 4;

    f32x4 acc[4][4];
    #pragma unroll
    for (int i = 0; i < 4; ++i)
        #pragma unroll
        for (int j = 0; j < 4; ++j)
            acc[i][j] = (f32x4){0.f, 0.f, 0.f, 0.f};

    const int srow = t >> 3;
    const int scol = (t & 7) * 4;

    for (int k0 = 0; k0 < 1024; k0 += 32) {
        #pragma unroll
        for (int p = 0; p < 4; ++p) {
            const int row = p * 32 + srow;
            const float4 av = *reinterpret_cast<const float4*>(
                A + (size_t)(m0 + row) * 1024 + k0 + scol);
            ushort4 a4;
            a4.x = f2b(av.x); a4.y = f2b(av.y); a4.z = f2b(av.z); a4.w = f2b(av.w);
            *reinterpret_cast<ushort4*>(&Ah[row * LDSTR + scol]) = a4;
            const float4 bv = *reinterpret_cast<const float4*>(
                B + (size_t)(n0 + row) * 1024 + k0 + scol);
            ushort4 b4;
            b4.x = f2b(bv.x); b4.y = f2b(bv.y); b4.z = f2b(bv.z); b4.w = f2b(bv.w);
            *reinterpret_cast<ushort4*>(&Bh[row * LDSTR + scol]) = b4;
        }
        __syncthreads();

        bf16x8 af[4], bfr[4];
        #pragma unroll
        for (int mi = 0; mi < 4; ++mi)
            af[mi] = *reinterpret_cast<const bf16x8*>(&Ah[(wm + mi * 16 + fr) * LDSTR + kq * 8]);
        #pragma unroll
        for (int ni = 0; ni < 4; ++ni)
            bfr[ni] = *reinterpret_cast<const bf16x8*>(&Bh[(wn + ni * 16 + fr) * LDSTR + kq * 8]);
        #pragma unroll
        for (int mi = 0; mi < 4; ++mi)
            #pragma unroll
            for (int ni = 0; ni < 4; ++ni)
                acc[mi][ni] = __builtin_amdgcn_mfma_f32_16x16x32_bf16(
                    af[mi], bfr[ni], acc[mi][ni], 0, 0, 0);
        __syncthreads();
    }

    const int crow0 = m0 + wm + kq * 4;
    const int ccol0 = n0 + wn + fr;
    #pragma unroll
    for (int mi = 0; mi < 4; ++mi)
        #pragma unroll
        for (int ni = 0; ni < 4; ++ni) {
            const int col = ccol0 + ni * 16;
            #pragma unroll
            for (int i = 0; i < 4; ++i)
                C[(size_t)(crow0 + mi * 16 + i) * 1024 + col] = acc[mi][ni][i];
        }
}

// ---------------------------------------------------------------------------
// Weight packing: Wkv[512][1024] = [Wk;Wv];  Whid[160][1024] = [w1|a1|v1]^T;
// w2T[1024][64], a2T[1024][64], v2T[1024][32] transposes.
// ---------------------------------------------------------------------------
__global__ __launch_bounds__(256) void pack_all(
    const float* __restrict__ Wk, const float* __restrict__ Wv,
    const float* __restrict__ w1, const float* __restrict__ a1,
    const float* __restrict__ v1, const float* __restrict__ w2,
    const float* __restrict__ a2, const float* __restrict__ v2,
    float* __restrict__ Wkv, float* __restrict__ Whid,
    float* __restrict__ w2T, float* __restrict__ a2T, float* __restrict__ v2T)
{
    const int blk = blockIdx.x, t = threadIdx.x;
    if (blk < 512) {
        const float* s = blk < 256 ? Wk + (size_t)blk * 1024
                                   : Wv + (size_t)(blk - 256) * 1024;
        const float4 v = *reinterpret_cast<const float4*>(s + t * 4);
        *reinterpret_cast<float4*>(Wkv + (size_t)blk * 1024 + t * 4) = v;
    } else if (blk < 672) {
        const int f = blk - 512;     // 0..159
        for (int c = t; c < 1024; c += 256) {
            float val;
            if (f < 64)       val = w1[c * 64 + f];
            else if (f < 128) val = a1[c * 64 + (f - 64)];
            else              val = v1[c * 32 + (f - 128)];
            Whid[f * 1024 + c] = val;
        }
    } else {
        const int c = blk - 672;     // 0..1023
        if (t < 64)       w2T[c * 64 + t]         = w2[t * 1024 + c];
        else if (t < 128) a2T[c * 64 + (t - 64)]  = a2[(t - 64) * 1024 + c];
        else if (t < 160) v2T[c * 32 + (t - 128)] = v2[(t - 128) * 1024 + c];
    }
}

// ---------------------------------------------------------------------------
// Slim fuse_pre: dd/aacc/vacc come precomputed (GEMM) in ddl/aal/vvl, which
// ALIAS the output buffers wdec/kf/vf (read idx then write idx — safe).
// ---------------------------------------------------------------------------
__global__ __launch_bounds__(256) void fuse_pre(
    const float* __restrict__ kv,
    const float* __restrict__ v_first, const float* __restrict__ mask,
    const float* __restrict__ w0, const float* __restrict__ a0,
    const float* __restrict__ v0,
    const float* __restrict__ k_k, const float* __restrict__ k_a,
    float* __restrict__ wdec, float* __restrict__ kf, float* __restrict__ vf,
    float* __restrict__ aab, float* __restrict__ bbb)
{
    const int n = blockIdx.x, t = threadIdx.x;
    const float m = mask[n];
    const bool live = m > 0.f;

    #pragma unroll
    for (int q = 0; q < 4; ++q) {
        const int c = q * 256 + t;
        const size_t idx = (size_t)n * 1024 + c;
        const float dd   = w0[c] + wdec[idx];   // ddl
        const float aacc = a0[c] + kf[idx];     // aal
        const float vacc = v0[c] + vf[idx];     // vvl

        const float u  = -dd;
        const float sp = fmaxf(u, 0.f) + log1pf(expf(-fabsf(u)));
        const float dec = expf(-expf(-sp - 0.6f));
        const float av = 1.f / (1.f + expf(-aacc));
        const float sv = 1.f / (1.f + expf(-vacc));

        const int  ck  = q * 64 + (c & 63);
        const float kr = kv[(size_t)n * 512 + ck];
        const float vr = kv[(size_t)n * 512 + 256 + ck];
        const float vfi = v_first[idx];
        const float vv  = vr + (vfi - vr) * sv;

        const float tkk = kr * k_k[c];
        float ss = tkk * tkk;
        #pragma unroll
        for (int off = 32; off > 0; off >>= 1) ss += __shfl_xor(ss, off, 64);
        const float kkv = tkk / fmaxf(sqrtf(ss), 1e-12f);

        wdec[idx] = live ? dec : 1.f;
        kf[idx]   = kr * (1.f + (av - 1.f) * k_a[c]) * m;
        vf[idx]   = vv * m;
        aab[idx]  = -kkv * m;
        bbb[idx]  = kkv * av * m;
    }
}

// ---------------------------------------------------------------------------
// WKV7: 256 blocks x 4 waves = 1024 waves; wave = (bh, 4 value-rows).
// Lane: row i = wib*4 + (lane>>4), channels c0=4*(lane&15) (float4).
// Row reduce = 4 DPP adds (VALU, no DS). Depth-4 register prefetch,
// y batched 4 steps.
// ---------------------------------------------------------------------------
__device__ __forceinline__ float qred16(float x) {
    x += __int_as_float(__builtin_amdgcn_update_dpp(
        0, __float_as_int(x), 0xB1, 0xF, 0xF, true));   // quad_perm xor1
    x += __int_as_float(__builtin_amdgcn_update_dpp(
        0, __float_as_int(x), 0x4E, 0xF, 0xF, true));   // quad_perm xor2
    x += __int_as_float(__builtin_amdgcn_update_dpp(
        0, __float_as_int(x), 0x141, 0xF, 0xF, true));  // row_half_mirror
    x += __int_as_float(__builtin_amdgcn_update_dpp(
        0, __float_as_int(x), 0x140, 0xF, 0xF, true));  // row_mirror
    return x;
}

__global__ __launch_bounds__(256, 1) void wkv7(
    const float* __restrict__ r, const float* __restrict__ wdec,
    const float* __restrict__ kf, const float* __restrict__ vf,
    const float* __restrict__ aab, const float* __restrict__ bbb,
    float* __restrict__ y)
{
    const int gw = blockIdx.x * 4 + (threadIdx.x >> 6);   // 0..1023
    const int bh = gw >> 4;                                // 0..63
    const int b = bh >> 4, h = bh & 15;
    const int wib = gw & 15;                               // 16 waves/bh
    const int lane = threadIdx.x & 63;
    const int li = lane & 15;
    const int i  = wib * 4 + (lane >> 4);                  // value row
    const int c0 = li * 4;
    const size_t cb = (size_t)b * (1024 * 1024) + (size_t)h * 64;

    float4 S = make_float4(0.f, 0.f, 0.f, 0.f);

    float4 dA, kA, aA, bA, rA; float vA;
    float4 dB, kB, aB, bB, rB; float vB;
    float4 dC, kC, aC, bC, rC; float vC;
    float4 dD, kD, aD, bD, rD; float vD;

#define LD(T, d_, k_, a_, b_, r_, v_)                                   \
    {   const size_t p_ = cb + (size_t)(T) * 1024;                      \
        d_ = *reinterpret_cast<const float4*>(wdec + p_ + c0);          \
        k_ = *reinterpret_cast<const float4*>(kf   + p_ + c0);          \
        a_ = *reinterpret_cast<const float4*>(aab  + p_ + c0);          \
        b_ = *reinterpret_cast<const float4*>(bbb  + p_ + c0);          \
        r_ = *reinterpret_cast<const float4*>(r    + p_ + c0);          \
        v_ = vf[p_ + i]; }

#define STEP(d_, k_, a_, b_, r_, v_, YOUT)                              \
    {   float sa_ = S.x * a_.x + S.y * a_.y + S.z * a_.z + S.w * a_.w;  \
        sa_ = qred16(sa_);                                              \
        S.x = S.x * d_.x + sa_ * b_.x + v_ * k_.x;                     \
        S.y = S.y * d_.y + sa_ * b_.y + v_ * k_.y;                     \
        S.z = S.z * d_.z + sa_ * b_.z + v_ * k_.z;                     \
        S.w = S.w * d_.w + sa_ * b_.w + v_ * k_.w;                     \
        float yv_ = S.x * r_.x + S.y * r_.y + S.z * r_.z + S.w * r_.w; \
        YOUT = qred16(yv_); }

    LD(0, dA, kA, aA, bA, rA, vA);
    LD(1, dB, kB, aB, bB, rB, vB);
    LD(2, dC, kC, aC, bC, rC, vC);
    LD(3, dD, kD, aD, bD, rD, vD);

    for (int t = 0; t < 1024; t += 4) {
        float y0, y1, y2, y3;
        const int t4 = t + 4 < 1024 ? t + 4 : 1023;
        const int t5 = t + 5 < 1024 ? t + 5 : 1023;
        const int t6 = t + 6 < 1024 ? t + 6 : 1023;
        const int t7 = t + 7 < 1024 ? t + 7 : 1023;
        STEP(dA, kA, aA, bA, rA, vA, y0);
        LD(t4, dA, kA, aA, bA, rA, vA);
        STEP(dB, kB, aB, bB, rB, vB, y1);
        LD(t5, dB, kB, aB, bB, rB, vB);
        STEP(dC, kC, aC, bC, rC, vC, y2);
        LD(t6, dC, kC, aC, bC, rC, vC);
        STEP(dD, kD, aD, bD, rD, vD, y3);
        LD(t7, dD, kD, aD, bD, rD, vD);
        if (li == 0) {
            const size_t yb = cb + (size_t)t * 1024 + i;
            y[yb]           = y0;
            y[yb + 1024]    = y1;
            y[yb + 2048]    = y2;
            y[yb + 3072]    = y3;
        }
    }
#undef LD
#undef STEP
}

// ---------------------------------------------------------------------------
// Post: groupnorm per (row, head) + rk*v residual
// ---------------------------------------------------------------------------
__global__ __launch_bounds__(256) void fuse_post(
    const float* __restrict__ y, const float* __restrict__ r,
    const float* __restrict__ kf, const float* __restrict__ vf,
    const float* __restrict__ r_k, const float* __restrict__ ln_g, const float* __restrict__ ln_b,
    float* __restrict__ yn)
{
    const int n = blockIdx.x, t = threadIdx.x;
    #pragma unroll
    for (int q = 0; q < 4; ++q) {
        const int c = q * 256 + t;
        const size_t idx = (size_t)n * 1024 + c;
        const float yv = y[idx];
        float s1 = yv, s2 = yv * yv;
        float rk = r[idx] * kf[idx] * r_k[c];
        #pragma unroll
        for (int off = 32; off > 0; off >>= 1) {
            s1 += __shfl_xor(s1, off, 64);
            s2 += __shfl_xor(s2, off, 64);
            rk += __shfl_xor(rk, off, 64);
        }
        const float mu  = s1 * (1.f / 64.f);
        const float var = s2 * (1.f / 64.f) - mu * mu;
        yn[idx] = (yv - mu) * rsqrtf(var + EPSV) * ln_g[c] + ln_b[c]
                  + rk * vf[idx];
    }
}

// ---------------------------------------------------------------------------
extern "C" void kernel_launch(void* const* d_in, const int* in_sizes, int n_in,
                              void* d_out, int out_size, void* d_ws, size_t ws_size,
                              hipStream_t stream)
{
    const float* x       = (const float*)d_in[0];
    const float* v_first = (const float*)d_in[1];
    const float* mask    = (const float*)d_in[2];
    const float* Wr      = (const float*)d_in[3];
    const float* Wk      = (const float*)d_in[4];
    const float* Wv      = (const float*)d_in[5];
    const float* Wo      = (const float*)d_in[6];
    const float* w0      = (const float*)d_in[7];
    const float* w1      = (const float*)d_in[8];
    const float* w2      = (const float*)d_in[9];
    const float* a0      = (const float*)d_in[10];
    const float* a1      = (const float*)d_in[11];
    const float* a2      = (const float*)d_in[12];
    const float* v0      = (const float*)d_in[13];
    const float* v1      = (const float*)d_in[14];
    const float* v2      = (const float*)d_in[15];
    const float* k_k     = (const float*)d_in[16];
    const float* k_a     = (const float*)d_in[17];
    const float* r_k     = (const float*)d_in[18];
    const float* ln_g    = (const float*)d_in[19];
    const float* ln_b    = (const float*)d_in[20];
    float* out = (float*)d_out;

    float* ws = (float*)d_ws;
    const size_t M4 = (size_t)NROWS * CCH;   // 4M elements
    float* rbuf = ws;
    float* wdec = ws + 1 * M4;   // pre-fuse_pre: ddl
    float* kf   = ws + 2 * M4;   // pre-fuse_pre: aal
    float* vf   = ws + 3 * M4;   // pre-fuse_pre: vvl
    float* aab  = ws + 4 * M4;   // post-wkv7: yn
    float* bbb  = ws + 5 * M4;
    float* ybuf = ws + 6 * M4;
    // region-6 temps (dead before wkv7 writes ybuf):
    float* kv   = ybuf;                          // [4096][512]
    float* hid  = kv   + (size_t)NROWS * 512;    // [4096][160]
    float* Wkv  = hid  + (size_t)NROWS * 160;    // [512][1024]
    float* Whid = Wkv  + (size_t)512 * 1024;     // [160][1024]
    float* w2T  = Whid + (size_t)160 * 1024;     // [1024][64]
    float* a2T  = w2T  + (size_t)1024 * 64;      // [1024][64]
    float* v2T  = a2T  + (size_t)1024 * 64;      // [1024][32]
    float* yn = aab;

    dim3 blk(256);
    pack_all<<<1696, blk, 0, stream>>>(Wk, Wv, w1, a1, v1, w2, a2, v2,
                                       Wkv, Whid, w2T, a2T, v2T);
    gemm_split<false><<<dim3(8, 32), blk, 0, stream>>>(
        x, 1024, Wr, 1024, rbuf, 1024, NROWS, 1024, 1024);
    gemm_split<false><<<dim3(4, 32), blk, 0, stream>>>(
        x, 1024, Wkv, 1024, kv, 512, NROWS, 512, 1024);
    gemm_split<true><<<dim3(2, 32), blk, 0, stream>>>(
        x, 1024, Whid, 1024, hid, 160, NROWS, 160, 1024);
    // stage-2: dd -> wdec(ddl), aa -> kf(aal), vv -> vf(vvl)
    gemm_split<false><<<dim3(8, 32), blk, 0, stream>>>(
        hid, 160, w2T, 64, wdec, 1024, NROWS, 1024, 64);
    gemm_split<false><<<dim3(8, 32), blk, 0, stream>>>(
        hid + 64, 160, a2T, 64, kf, 1024, NROWS, 1024, 64);
    gemm_split<false><<<dim3(8, 32), blk, 0, stream>>>(
        hid + 128, 160, v2T, 32, vf, 1024, NROWS, 1024, 32);
    fuse_pre<<<NROWS, blk, 0, stream>>>(kv, v_first, mask, w0, a0, v0,
                                        k_k, k_a, wdec, kf, vf, aab, bbb);
    wkv7<<<256, blk, 0, stream>>>(rbuf, wdec, kf, vf, aab, bbb, ybuf);
    fuse_post<<<NROWS, blk, 0, stream>>>(ybuf, rbuf, kf, vf, r_k, ln_g, ln_b, yn);
    gemm_mfma<<<dim3(8, 32), blk, 0, stream>>>(yn, Wo, out, NROWS, 1024, 1024);
    hipMemcpyAsync(out + M4, v_first, M4 * sizeof(float),
                   hipMemcpyDeviceToDevice, stream);
}